// Round 2
// baseline (4753.490 us; speedup 1.0000x reference)
//
#include <hip/hip_runtime.h>
#include <hip/hip_fp16.h>

#define NB 128
#define NT 1024
#define DIN 64
#define NP 128
#define NG 512
#define NO 64

#ifndef __has_builtin
#define __has_builtin(x) 0
#endif
#if __has_builtin(__builtin_amdgcn_fdot2)
#define HAVE_FDOT2 1
#else
#define HAVE_FDOT2 0
#endif

typedef _Float16 h2v __attribute__((ext_vector_type(2)));

__device__ __forceinline__ float sigf(float x) {
  return 1.0f / (1.0f + __expf(-x));
}
__device__ __forceinline__ float tanh_fast(float x) {
  float ax = fabsf(x);
  float e = __expf(-2.0f * ax);
  float t = (1.0f - e) / (1.0f + e);
  return copysignf(t, x);
}
__device__ __forceinline__ unsigned packh2(float a, float b) {
  return (unsigned)__half_as_ushort(__float2half_rn(a)) |
         ((unsigned)__half_as_ushort(__float2half_rn(b)) << 16);
}
__device__ __forceinline__ float dot2(unsigned wu, unsigned xu, float acc) {
#if HAVE_FDOT2
  return __builtin_amdgcn_fdot2(__builtin_bit_cast(h2v, wu),
                                __builtin_bit_cast(h2v, xu), acc, false);
#else
  float wl = __half2float(__ushort_as_half((unsigned short)(wu & 0xffffu)));
  float wh = __half2float(__ushort_as_half((unsigned short)(wu >> 16)));
  float xl = __half2float(__ushort_as_half((unsigned short)(xu & 0xffffu)));
  float xh = __half2float(__ushort_as_half((unsigned short)(xu >> 16)));
  return fmaf(wh, xh, fmaf(wl, xl, acc));
#endif
}

// Fused 2-layer LSTM + FC. 1 block / batch row, 1024 threads.
// Threads [0,512): layer-0 gate rows, step s.  Threads [512,1024): layer-1
// gate rows, step s-1 (h0 passed through a 2-slot LDS ring).  FC of h1_{s-2}
// on layer-0 threads [256,512) (fcw in their registers); out row s-2 stored
// in phase 2.  Two barriers per merged step; 1026 merged steps.
__global__ __launch_bounds__(1024, 4) void lstm_fused(
    const float* __restrict__ x,      // [B,T,64]
    const float* __restrict__ wih0,   // [512,64]
    const float* __restrict__ whh0,   // [512,128]
    const float* __restrict__ wih1,   // [512,128]
    const float* __restrict__ whh1,   // [512,128]
    const float* __restrict__ bih,    // [2,512]
    const float* __restrict__ bhh,    // [2,512]
    const float* __restrict__ fcw,    // [64,128]
    const float* __restrict__ fcb,    // [64]
    float* __restrict__ out)          // [B,T,64]
{
  const int b = blockIdx.x;
  const int tid = threadIdx.x;

  __shared__ __align__(16) unsigned xh[2][DIN / 2];   // x_t as f16 pairs
  __shared__ __align__(16) __half ring_h[2][NP];      // h0 ring (f16)
  __shared__ __align__(16) __half hs1_h[NP];          // h1 prev (f16)
  __shared__ float gs0[NG];
  __shared__ float gs1[NG];
  __shared__ float fcp[NO][5];                        // FC partials (+pad)

  // ---- per-thread weights (packed f16 pairs, register-resident) ----
  unsigned wi[64], wh[64];   // L0 uses wi[0..31]; L1 uses all 64 of each
  unsigned fcwp[16];
  float biasv = 0.f, fcbv = 0.f;

  if (tid < NG) {
    const int r = tid;
#pragma unroll
    for (int k = 0; k < DIN / 4; ++k) {
      float4 v = *(const float4*)&wih0[r * DIN + 4 * k];
      wi[2 * k] = packh2(v.x, v.y);
      wi[2 * k + 1] = packh2(v.z, v.w);
    }
#pragma unroll
    for (int k = 0; k < NP / 4; ++k) {
      float4 v = *(const float4*)&whh0[r * NP + 4 * k];
      wh[2 * k] = packh2(v.x, v.y);
      wh[2 * k + 1] = packh2(v.z, v.w);
    }
    biasv = bih[r] + bhh[r];
    if (tid >= 256) {  // FC thread: o = tid&63, quarter q = (tid>>6)-4
      int o = tid & 63, q = (tid >> 6) - 4;
#pragma unroll
      for (int k = 0; k < 8; ++k) {
        float4 v = *(const float4*)&fcw[o * NP + 32 * q + 4 * k];
        fcwp[2 * k] = packh2(v.x, v.y);
        fcwp[2 * k + 1] = packh2(v.z, v.w);
      }
    }
    if (tid >= 128 && tid < 192) fcbv = fcb[tid - 128];
  } else {
    const int r = tid - NG;
#pragma unroll
    for (int k = 0; k < NP / 4; ++k) {
      float4 v = *(const float4*)&wih1[r * NP + 4 * k];
      wi[2 * k] = packh2(v.x, v.y);
      wi[2 * k + 1] = packh2(v.z, v.w);
    }
#pragma unroll
    for (int k = 0; k < NP / 4; ++k) {
      float4 v = *(const float4*)&whh1[r * NP + 4 * k];
      wh[2 * k] = packh2(v.x, v.y);
      wh[2 * k + 1] = packh2(v.z, v.w);
    }
    biasv = bih[NG + r] + bhh[NG + r];
  }

  // ---- LDS init ----
  if (tid < NP) {
    ring_h[1][tid] = __float2half(0.f);  // h0_{-1}
    hs1_h[tid] = __float2half(0.f);      // h1_{-1}
  }
  if (tid < 16) {
    float4 v = *(const float4*)&x[(size_t)b * NT * DIN + 4 * tid];
    uint2 u;
    u.x = packh2(v.x, v.y);
    u.y = packh2(v.z, v.w);
    *(uint2*)&xh[0][2 * tid] = u;
  }
  float c0 = 0.f, c1 = 0.f;
  __syncthreads();

  float4 xpre;
  for (int s = 0; s <= NT + 1; ++s) {
    // prefetch x_{s+1} (consumed at end of phase 2)
    if (tid < 16 && s + 1 < NT)
      xpre = *(const float4*)&x[(size_t)b * NT * DIN + (size_t)(s + 1) * DIN + 4 * tid];

    // ---------------- phase 1: dots ----------------
    if (tid < NG) {
      if (s < NT) {  // layer-0 gates for step s
        float a0 = biasv, a1 = 0.f, a2 = 0.f, a3 = 0.f;
        const uint4* xc = (const uint4*)xh[s & 1];
#pragma unroll
        for (int k = 0; k < 8; ++k) {
          uint4 u = xc[k];
          a0 = dot2(wi[4 * k + 0], u.x, a0);
          a1 = dot2(wi[4 * k + 1], u.y, a1);
          a2 = dot2(wi[4 * k + 2], u.z, a2);
          a3 = dot2(wi[4 * k + 3], u.w, a3);
        }
        const uint4* hc = (const uint4*)ring_h[(s - 1) & 1];  // h0_{s-1}
#pragma unroll
        for (int k = 0; k < 16; ++k) {
          uint4 u = hc[k];
          a0 = dot2(wh[4 * k + 0], u.x, a0);
          a1 = dot2(wh[4 * k + 1], u.y, a1);
          a2 = dot2(wh[4 * k + 2], u.z, a2);
          a3 = dot2(wh[4 * k + 3], u.w, a3);
        }
        gs0[tid] = (a0 + a1) + (a2 + a3);
      }
      if (tid >= 256 && s >= 2) {  // FC partials of h1_{s-2}
        int q = (tid >> 6) - 4;
        const uint4* hq = (const uint4*)&hs1_h[32 * q];
        float p0 = 0.f, p1 = 0.f, p2 = 0.f, p3 = 0.f;
#pragma unroll
        for (int k = 0; k < 4; ++k) {
          uint4 u = hq[k];
          p0 = dot2(fcwp[4 * k + 0], u.x, p0);
          p1 = dot2(fcwp[4 * k + 1], u.y, p1);
          p2 = dot2(fcwp[4 * k + 2], u.z, p2);
          p3 = dot2(fcwp[4 * k + 3], u.w, p3);
        }
        fcp[tid & 63][q] = (p0 + p1) + (p2 + p3);
      }
    } else if (s >= 1 && s <= NT) {  // layer-1 gates for step s-1
      const int r1 = tid - NG;
      float a0 = biasv, a1 = 0.f, a2 = 0.f, a3 = 0.f;
      const uint4* ic = (const uint4*)ring_h[(s - 1) & 1];  // h0_{s-1}
#pragma unroll
      for (int k = 0; k < 16; ++k) {
        uint4 u = ic[k];
        a0 = dot2(wi[4 * k + 0], u.x, a0);
        a1 = dot2(wi[4 * k + 1], u.y, a1);
        a2 = dot2(wi[4 * k + 2], u.z, a2);
        a3 = dot2(wi[4 * k + 3], u.w, a3);
      }
      const uint4* hc = (const uint4*)hs1_h;  // h1_{s-2}
#pragma unroll
      for (int k = 0; k < 16; ++k) {
        uint4 u = hc[k];
        a0 = dot2(wh[4 * k + 0], u.x, a0);
        a1 = dot2(wh[4 * k + 1], u.y, a1);
        a2 = dot2(wh[4 * k + 2], u.z, a2);
        a3 = dot2(wh[4 * k + 3], u.w, a3);
      }
      gs1[r1] = (a0 + a1) + (a2 + a3);
    }
    __syncthreads();  // A: gates + FC partials ready

    // ---------------- phase 2: cell updates / output ----------------
    if (tid < NP && s < NT) {  // layer-0 cell
      float gi = gs0[tid], gf = gs0[tid + NP];
      float gg = gs0[tid + 2 * NP], go = gs0[tid + 3 * NP];
      c0 = sigf(gf) * c0 + sigf(gi) * tanh_fast(gg);
      ring_h[s & 1][tid] = __float2half(sigf(go) * tanh_fast(c0));
    }
    if (tid >= NP && tid < NP + NO && s >= 2) {  // FC final sum, row s-2
      int o = tid - NP;
      out[(size_t)b * NT * NO + (size_t)(s - 2) * NO + o] =
          ((fcp[o][0] + fcp[o][1]) + (fcp[o][2] + fcp[o][3])) + fcbv;
    }
    if (tid >= NG && tid < NG + NP && s >= 1 && s <= NT) {  // layer-1 cell
      int r1 = tid - NG;
      float gi = gs1[r1], gf = gs1[r1 + NP];
      float gg = gs1[r1 + 2 * NP], go = gs1[r1 + 3 * NP];
      c1 = sigf(gf) * c1 + sigf(gi) * tanh_fast(gg);
      hs1_h[r1] = __float2half(sigf(go) * tanh_fast(c1));
    }
    if (tid < 16 && s + 1 < NT) {  // stage x_{s+1}
      uint2 u;
      u.x = packh2(xpre.x, xpre.y);
      u.y = packh2(xpre.z, xpre.w);
      *(uint2*)&xh[(s + 1) & 1][2 * tid] = u;
    }
    __syncthreads();  // B: h_t / x_{s+1} staged
  }
}

extern "C" void kernel_launch(void* const* d_in, const int* in_sizes, int n_in,
                              void* d_out, int out_size, void* d_ws, size_t ws_size,
                              hipStream_t stream) {
  const float* x     = (const float*)d_in[0];
  const float* w_ih0 = (const float*)d_in[1];
  const float* w_hh0 = (const float*)d_in[2];
  const float* w_ih1 = (const float*)d_in[3];
  const float* w_hh1 = (const float*)d_in[4];
  const float* b_ih  = (const float*)d_in[5];
  const float* b_hh  = (const float*)d_in[6];
  const float* fc_w  = (const float*)d_in[7];
  const float* fc_b  = (const float*)d_in[8];
  float* out = (float*)d_out;

  lstm_fused<<<NB, 1024, 0, stream>>>(x, w_ih0, w_hh0, w_ih1, w_hh1,
                                      b_ih, b_hh, fc_w, fc_b, out);
}

// Round 3
// 1473.665 us; speedup vs baseline: 3.2256x; 3.2256x over previous
//
#include <hip/hip_runtime.h>

#define NT 1024
#define RING 256
#define RMAR 24

typedef _Float16 half8 __attribute__((ext_vector_type(8)));
typedef _Float16 half4 __attribute__((ext_vector_type(4)));
typedef float f32x4 __attribute__((ext_vector_type(4)));

__device__ __forceinline__ f32x4 MFMA(half8 a, half8 b, f32x4 c) {
  return __builtin_amdgcn_mfma_f32_16x16x32_f16(a, b, c, 0, 0, 0);
}
__device__ __forceinline__ float sigf(float x) {
  return __builtin_amdgcn_rcpf(1.0f + __expf(-x));
}
__device__ __forceinline__ float tanhf2(float x) {
  float ax = fabsf(x);
  float e = __expf(-2.0f * ax);
  float t = (1.0f - e) * __builtin_amdgcn_rcpf(1.0f + e);
  return copysignf(t, x);
}
__device__ __forceinline__ half8 cvt8(float4 c0, float4 c1) {
  half8 hv;
  hv[0] = (_Float16)c0.x; hv[1] = (_Float16)c0.y;
  hv[2] = (_Float16)c0.z; hv[3] = (_Float16)c0.w;
  hv[4] = (_Float16)c1.x; hv[5] = (_Float16)c1.y;
  hv[6] = (_Float16)c1.z; hv[7] = (_Float16)c1.w;
  return hv;
}
struct U2 { unsigned long long a, b; };

// Repack x [B,T,64] f32 -> f16 B-fragments Xf[g][t][kt][lane][8]
// k-perm within tile: kk(lane,j) = (j>>2)*16 + (lane>>4)*4 + (j&3)
__global__ __launch_bounds__(256) void prep_x(const float* __restrict__ x,
                                              _Float16* __restrict__ Xf) {
  int t0 = blockIdx.x * 256 + threadIdx.x;
  int l = t0 & 63;
  int fid = t0 >> 6;                  // ((g*NT + t)*2 + kt)
  int kt = fid & 1;
  int t = (fid >> 1) & (NT - 1);
  int g = fid >> 11;
  int bt = g * 16 + (l & 15);
  int kb = kt * 32 + (l >> 4) * 4;
  const float* src = x + ((size_t)bt * NT + (size_t)t) * 64 + kb;
  float4 v0 = *(const float4*)src;
  float4 v1 = *(const float4*)(src + 16);
  *(half8*)(Xf + (size_t)fid * 512 + l * 8) = cvt8(v0, v1);
}

// 16 blocks of 512 threads: blocks 0..7 = layer-0 producer for batch group g,
// blocks 8..15 = layer-1 + FC consumer for group g. Handoff via global
// fragment ring + device-scope flags. Weights live in MFMA A-fragments in
// registers; per-step GEMM G[512,16] = W x Z via mfma_f32_16x16x32_f16.
// Wave w owns M-tiles {w, w+8, w+16, w+24} => i,f,g,o of each row are
// lane-local (C layout: col=lane&15, row=(lane>>4)*4+reg  [m89/m91]).
__global__ __launch_bounds__(512, 2) void lstm_main(
    const float* __restrict__ wih0, const float* __restrict__ whh0,
    const float* __restrict__ wih1, const float* __restrict__ whh1,
    const float* __restrict__ bih, const float* __restrict__ bhh,
    const float* __restrict__ fcw, const float* __restrict__ fcb,
    const _Float16* __restrict__ Xf, _Float16* __restrict__ ring,
    unsigned* __restrict__ prog, unsigned* __restrict__ consread,
    float* __restrict__ out) {
  const int tid = threadIdx.x;
  const int w = tid >> 6, l = tid & 63;
  const int n = l & 15, lg = l >> 4;
  const bool producer = blockIdx.x < 8;
  const int g = blockIdx.x & 7;

  __shared__ _Float16 hfrag[2][4][64][8];  // 2-slot ring of h B-fragments

  if (tid < 256) {  // h_{-1} = 0 (slot 1 read at s=0)
    half8 z = {0, 0, 0, 0, 0, 0, 0, 0};
    ((half8*)&hfrag[1][0][0][0])[tid] = z;
  }

  if (producer) {
    // ---- layer-0 weights as A-fragments: Z = [x(64); h0(128)], 6 K-tiles
    half8 A[4][6];
    f32x4 bias[4];
#pragma unroll
    for (int q = 0; q < 4; ++q) {
      int row = (w + 8 * q) * 16 + n;
#pragma unroll
      for (int kt = 0; kt < 6; ++kt) {
        int kb = kt * 32 + lg * 4;
        const float* wp = (kt < 2) ? (wih0 + (size_t)row * 64 + kb)
                                   : (whh0 + (size_t)row * 128 + (kb - 64));
        A[q][kt] = cvt8(*(const float4*)wp, *(const float4*)(wp + 16));
      }
      int rb = (w + 8 * q) * 16 + lg * 4;
      f32x4 bv;
#pragma unroll
      for (int r = 0; r < 4; ++r) bv[r] = bih[rb + r] + bhh[rb + r];
      bias[q] = bv;
    }
    const _Float16* XfG = Xf + (size_t)g * NT * 1024;
    _Float16* ringG = ring + (size_t)g * RING * 2048;
    half8 x0 = *(const half8*)(XfG + l * 8);
    half8 x1 = *(const half8*)(XfG + 512 + l * 8);
    f32x4 cst = {0.f, 0.f, 0.f, 0.f};
    unsigned Cc = 0;
    __syncthreads();
    for (int s = 0; s < NT; ++s) {
      half8 xn0, xn1;
      if (s + 1 < NT) {
        const _Float16* p = XfG + (size_t)(s + 1) * 1024 + l * 8;
        xn0 = *(const half8*)p;
        xn1 = *(const half8*)(p + 512);
      }
      // backpressure vs consumer (per wave, every 8 steps)
      if ((s & 7) == 0 && s >= RING - RMAR) {
        while (Cc + (RING - RMAR) <= (unsigned)s) {
          unsigned pv = 0;
          if (l == 0)
            pv = __hip_atomic_load(&consread[g], __ATOMIC_RELAXED,
                                   __HIP_MEMORY_SCOPE_AGENT);
          Cc = (unsigned)__builtin_amdgcn_readfirstlane((int)pv);
          if (Cc + (RING - RMAR) <= (unsigned)s) __builtin_amdgcn_s_sleep(8);
        }
      }
      f32x4 acc[4];
#pragma unroll
      for (int q = 0; q < 4; ++q) acc[q] = bias[q];
#pragma unroll
      for (int q = 0; q < 4; ++q) acc[q] = MFMA(A[q][0], x0, acc[q]);
#pragma unroll
      for (int q = 0; q < 4; ++q) acc[q] = MFMA(A[q][1], x1, acc[q]);
      const int rd = (s & 1) ^ 1;
#pragma unroll
      for (int kt = 0; kt < 4; ++kt) {
        half8 b = *(const half8*)&hfrag[rd][kt][l][0];
#pragma unroll
        for (int q = 0; q < 4; ++q) acc[q] = MFMA(A[q][2 + kt], b, acc[q]);
      }
      half4 hh;
#pragma unroll
      for (int r = 0; r < 4; ++r) {
        float iv = sigf(acc[0][r]), fv = sigf(acc[1][r]);
        float gv = tanhf2(acc[2][r]), ov = sigf(acc[3][r]);
        cst[r] = fv * cst[r] + iv * gv;
        hh[r] = (_Float16)(ov * tanhf2(cst[r]));
      }
      // h-frag: self-lane slot, K-tile w>>1, 8B half w&1 (derivation in notes)
      *(half4*)&hfrag[s & 1][w >> 1][l][(w & 1) * 4] = hh;
      unsigned long long uh = __builtin_bit_cast(unsigned long long, hh);
      unsigned long long* rp =
          (unsigned long long*)(ringG + (size_t)(s & (RING - 1)) * 2048 +
                                (w >> 1) * 512 + l * 8 + (w & 1) * 4);
      __hip_atomic_store(rp, uh, __ATOMIC_RELAXED, __HIP_MEMORY_SCOPE_AGENT);
      __syncthreads();  // also drains vmcnt (HIP __syncthreads semantics)
      if (tid == 0)
        __hip_atomic_store(&prog[g], (unsigned)(s + 1), __ATOMIC_RELEASE,
                           __HIP_MEMORY_SCOPE_AGENT);
      x0 = xn0;
      x1 = xn1;
    }
  } else {
    // ---- layer-1 weights: Z = [h0(128); h1(128)], 8 K-tiles; FC on waves 0-3
    half8 A[4][8], FCA[4];
    f32x4 bias[4], fcbv = {0.f, 0.f, 0.f, 0.f};
    const bool W4 = (w < 4);
#pragma unroll
    for (int q = 0; q < 4; ++q) {
      int row = (w + 8 * q) * 16 + n;
#pragma unroll
      for (int kt = 0; kt < 8; ++kt) {
        int kb = kt * 32 + lg * 4;
        const float* wp = (kt < 4) ? (wih1 + (size_t)row * 128 + kb)
                                   : (whh1 + (size_t)row * 128 + (kb - 128));
        A[q][kt] = cvt8(*(const float4*)wp, *(const float4*)(wp + 16));
      }
      int rb = (w + 8 * q) * 16 + lg * 4;
      f32x4 bv;
#pragma unroll
      for (int r = 0; r < 4; ++r) bv[r] = bih[512 + rb + r] + bhh[512 + rb + r];
      bias[q] = bv;
    }
    if (W4) {
      int row = w * 16 + n;
#pragma unroll
      for (int kt = 0; kt < 4; ++kt) {
        int kb = kt * 32 + lg * 4;
        const float* wp = fcw + (size_t)row * 128 + kb;
        FCA[kt] = cvt8(*(const float4*)wp, *(const float4*)(wp + 16));
      }
      fcbv = *(const f32x4*)(fcb + w * 16 + lg * 4);
    }
    const _Float16* ringG = ring + (size_t)g * RING * 2048;
    unsigned Pc = 0;
    while (Pc < 1) {
      unsigned pv = 0;
      if (l == 0)
        pv = __hip_atomic_load(&prog[g], __ATOMIC_ACQUIRE,
                               __HIP_MEMORY_SCOPE_AGENT);
      Pc = (unsigned)__builtin_amdgcn_readfirstlane((int)pv);
      if (Pc < 1) __builtin_amdgcn_s_sleep(8);
    }
    half8 h0c[4];
#pragma unroll
    for (int kt = 0; kt < 4; ++kt) {
      const unsigned long long* rp =
          (const unsigned long long*)(ringG + kt * 512 + l * 8);
      U2 uu;
      uu.a = __hip_atomic_load(rp, __ATOMIC_RELAXED, __HIP_MEMORY_SCOPE_AGENT);
      uu.b = __hip_atomic_load(rp + 1, __ATOMIC_RELAXED, __HIP_MEMORY_SCOPE_AGENT);
      h0c[kt] = __builtin_bit_cast(half8, uu);
    }
    f32x4 cst = {0.f, 0.f, 0.f, 0.f};
    float* outG = out + ((size_t)(g * 16 + n) * NT) * 64 + w * 16 + lg * 4;
    __syncthreads();
    for (int s = 0; s <= NT; ++s) {
      f32x4 acc[4], afc = fcbv;
      if (s < NT) {
#pragma unroll
        for (int q = 0; q < 4; ++q) acc[q] = bias[q];
#pragma unroll
        for (int kt = 0; kt < 4; ++kt)
#pragma unroll
          for (int q = 0; q < 4; ++q) acc[q] = MFMA(A[q][kt], h0c[kt], acc[q]);
      }
      const int rd = (s & 1) ^ 1;
#pragma unroll
      for (int kt = 0; kt < 4; ++kt) {
        half8 b = *(const half8*)&hfrag[rd][kt][l][0];  // h1_{s-1}
        if (s < NT) {
#pragma unroll
          for (int q = 0; q < 4; ++q) acc[q] = MFMA(A[q][4 + kt], b, acc[q]);
        }
        if (W4) afc = MFMA(FCA[kt], b, afc);  // FC of h1_{s-1}
      }
      if (W4 && s >= 1) *(f32x4*)(outG + (size_t)(s - 1) * 64) = afc;
      half8 h0n[4];
      if (s + 1 < NT) {  // prefetch h0_{s+1} (agent-scope: cross-XCD fresh)
        while (Pc < (unsigned)(s + 2)) {
          unsigned pv = 0;
          if (l == 0)
            pv = __hip_atomic_load(&prog[g], __ATOMIC_ACQUIRE,
                                   __HIP_MEMORY_SCOPE_AGENT);
          Pc = (unsigned)__builtin_amdgcn_readfirstlane((int)pv);
          if (Pc < (unsigned)(s + 2)) __builtin_amdgcn_s_sleep(8);
        }
        const _Float16* rbase =
            ringG + (size_t)((s + 1) & (RING - 1)) * 2048 + l * 8;
#pragma unroll
        for (int kt = 0; kt < 4; ++kt) {
          const unsigned long long* rp =
              (const unsigned long long*)(rbase + kt * 512);
          U2 uu;
          uu.a = __hip_atomic_load(rp, __ATOMIC_RELAXED, __HIP_MEMORY_SCOPE_AGENT);
          uu.b = __hip_atomic_load(rp + 1, __ATOMIC_RELAXED, __HIP_MEMORY_SCOPE_AGENT);
          h0n[kt] = __builtin_bit_cast(half8, uu);
        }
      }
      if (s < NT) {
        half4 hh;
#pragma unroll
        for (int r = 0; r < 4; ++r) {
          float iv = sigf(acc[0][r]), fv = sigf(acc[1][r]);
          float gv = tanhf2(acc[2][r]), ov = sigf(acc[3][r]);
          cst[r] = fv * cst[r] + iv * gv;
          hh[r] = (_Float16)(ov * tanhf2(cst[r]));
        }
        *(half4*)&hfrag[s & 1][w >> 1][l][(w & 1) * 4] = hh;
      }
      if (tid == 0)
        __hip_atomic_store(&consread[g], (unsigned)(s + 1), __ATOMIC_RELAXED,
                           __HIP_MEMORY_SCOPE_AGENT);
      __syncthreads();
      if (s + 1 < NT) {
#pragma unroll
        for (int kt = 0; kt < 4; ++kt) h0c[kt] = h0n[kt];
      }
    }
  }
}

extern "C" void kernel_launch(void* const* d_in, const int* in_sizes, int n_in,
                              void* d_out, int out_size, void* d_ws, size_t ws_size,
                              hipStream_t stream) {
  const float* x     = (const float*)d_in[0];
  const float* w_ih0 = (const float*)d_in[1];
  const float* w_hh0 = (const float*)d_in[2];
  const float* w_ih1 = (const float*)d_in[3];
  const float* w_hh1 = (const float*)d_in[4];
  const float* b_ih  = (const float*)d_in[5];
  const float* b_hh  = (const float*)d_in[6];
  const float* fc_w  = (const float*)d_in[7];
  const float* fc_b  = (const float*)d_in[8];

  _Float16* Xf   = (_Float16*)d_ws;                                  // 16 MB
  _Float16* ring = (_Float16*)((char*)d_ws + (16u << 20));           // 8 MB
  unsigned* flags = (unsigned*)((char*)d_ws + (24u << 20));          // 64 B

  hipMemsetAsync(flags, 0, 64, stream);
  prep_x<<<4096, 256, 0, stream>>>(x, Xf);
  lstm_main<<<16, 512, 0, stream>>>(w_ih0, w_hh0, w_ih1, w_hh1, b_ih, b_hh,
                                    fc_w, fc_b, Xf, ring, flags, flags + 8,
                                    (float*)d_out);
}